// Round 2
// baseline (75.802 us; speedup 1.0000x reference)
//
#include <hip/hip_runtime.h>

#define CHUNK    2048
#define NTHREADS 256
#define EPT      8   // elements per thread; CHUNK = NTHREADS * EPT

// constants from the reference
#define C_TREND   0.6f
#define C_DETAIL  0.85f
#define C_SPIKE_T 3.5f
#define C_SPIKE_D 0.35f
#define C_EPS     1e-6f

__device__ __forceinline__ float reflect_load(const float* __restrict__ rp, int g, int L) {
    if (g < 0) g = -g;
    else if (g >= L) g = 2 * L - 2 - g;
    return rp[g];
}

// Block-wide deterministic reduction of a row's partials -> threshold.
// Every block computes the identical value (same order of operations).
__device__ __forceinline__ float block_thr(const double* __restrict__ p, int bpr, int L) {
    const double2* p2 = reinterpret_cast<const double2*>(p);
    double s = 0.0, s2 = 0.0;
    for (int i = threadIdx.x; i < bpr; i += NTHREADS) {
        double2 v = p2[i];
        s += v.x; s2 += v.y;
    }
    #pragma unroll
    for (int off = 32; off > 0; off >>= 1) {
        s  += __shfl_down(s, off);
        s2 += __shfl_down(s2, off);
    }
    __shared__ double lds[8];
    __shared__ float thr_s;
    int wid = threadIdx.x >> 6, lane = threadIdx.x & 63;
    if (lane == 0) { lds[wid * 2] = s; lds[wid * 2 + 1] = s2; }
    __syncthreads();
    if (threadIdx.x == 0) {
        double ts  = lds[0] + lds[2] + lds[4] + lds[6];
        double ts2 = lds[1] + lds[3] + lds[5] + lds[7];
        double n = (double)L;
        double var = (ts2 - ts * ts / n) / (n - 1.0);
        float stdv = (float)sqrt(fmax(var, 0.0));
        thr_s = fmaxf(stdv, C_EPS) * C_SPIKE_T;
    }
    __syncthreads();
    return thr_s;
}

// Block reduce (s, s2) and write one partial pair per block.
__device__ __forceinline__ void block_partial_out(double s, double s2, double* __restrict__ partials) {
    #pragma unroll
    for (int off = 32; off > 0; off >>= 1) {
        s  += __shfl_down(s, off);
        s2 += __shfl_down(s2, off);
    }
    __shared__ double lds2[8];
    int wid = threadIdx.x >> 6, lane = threadIdx.x & 63;
    if (lane == 0) { lds2[wid * 2] = s; lds2[wid * 2 + 1] = s2; }
    __syncthreads();
    if (threadIdx.x == 0) {
        double ts  = lds2[0] + lds2[2] + lds2[4] + lds2[6];
        double ts2 = lds2[1] + lds2[3] + lds2[5] + lds2[7];
        partials[(size_t)blockIdx.x * 2 + 0] = ts;
        partials[(size_t)blockIdx.x * 2 + 1] = ts2;
    }
}

// ---- Stage 1: per-block partial sums of pass-1 residual (r, r^2) in double ----
__global__ __launch_bounds__(NTHREADS) void reduce1_kernel(
    const float* __restrict__ in, double* __restrict__ partials, int L, int bpr) {
    int row = blockIdx.x / bpr;
    int chunk = blockIdx.x % bpr;
    const float* rp = in + (size_t)row * L;
    int o = chunk * CHUNK + threadIdx.x * EPT;

    // need elements [o-2, o+10) -> load aligned window [o-4, o+12)
    float w[16];
    if (o >= 4 && o + 12 <= L) {
        const float4* p = reinterpret_cast<const float4*>(rp + o - 4);
        #pragma unroll
        for (int j = 0; j < 4; ++j) {
            float4 v = p[j];
            w[4*j+0] = v.x; w[4*j+1] = v.y; w[4*j+2] = v.z; w[4*j+3] = v.w;
        }
    } else {
        #pragma unroll
        for (int j = 0; j < 16; ++j) w[j] = reflect_load(rp, o - 4 + j, L);
    }

    double s = 0.0, s2 = 0.0;
    float s5 = w[2] + w[3] + w[4] + w[5] + w[6];
    #pragma unroll
    for (int k = 0; k < EPT; ++k) {
        float local = s5 * 0.2f;
        float r = w[4 + k] - local;
        s += (double)r;
        s2 = fma((double)r, (double)r, s2);
        if (k < EPT - 1) s5 += w[7 + k] - w[2 + k];
    }
    block_partial_out(s, s2, partials);
}

// scalar (boundary) computation of pass-1 output at logical position p (reflect-indexed)
__device__ float xp1_scalar(const float* __restrict__ rp, int L, int p, float thr) {
    if (p < 0) p = -p;
    else if (p >= L) p = 2 * L - 2 - p;
    float s5 = 0.f, s11 = 0.f;
    #pragma unroll
    for (int k = -5; k <= 5; ++k) {
        float v = reflect_load(rp, p + k, L);
        s11 += v;
        if (k >= -2 && k <= 2) s5 += v;
    }
    float local = s5 * 0.2f;
    float trend = s11 * (1.0f / 11.0f);
    float r = rp[p] - local;
    r = (fabsf(r) > thr) ? r * C_SPIKE_D : r;
    return (1.0f - C_TREND) * local + C_TREND * trend + C_DETAIL * r;
}

// ---- Stage 2: pass-1 apply (reads partials1 for thr) + pass-2 residual reduce ----
__global__ __launch_bounds__(NTHREADS) void fused_apply1_kernel(
    const float* __restrict__ in, float* __restrict__ xp1,
    const double* __restrict__ partials1, double* __restrict__ partials2,
    int L, int bpr) {
    int row = blockIdx.x / bpr;
    int chunk = blockIdx.x % bpr;
    const float* rp = in + (size_t)row * L;

    float thr = block_thr(partials1 + (size_t)row * bpr * 2, bpr, L);

    int o = chunk * CHUNK + threadIdx.x * EPT;

    // xv[j] = xp1 at logical position o-2+j, j in [0,12)
    float xv[12];
    if (o >= 8 && o + 16 <= L) {
        float w[24];  // x[o-8 .. o+15]
        const float4* p = reinterpret_cast<const float4*>(rp + o - 8);
        #pragma unroll
        for (int j = 0; j < 6; ++j) {
            float4 v = p[j];
            w[4*j+0] = v.x; w[4*j+1] = v.y; w[4*j+2] = v.z; w[4*j+3] = v.w;
        }
        float s5  = w[4] + w[5] + w[6] + w[7] + w[8];          // x[o-4..o]
        float s11 = w[1] + w[2] + w[3] + w[4] + w[5] + w[6]
                  + w[7] + w[8] + w[9] + w[10] + w[11];        // x[o-7..o+3]
        #pragma unroll
        for (int j = 0; j < 12; ++j) {
            float local = s5 * 0.2f;
            float trend = s11 * (1.0f / 11.0f);
            float r = w[6 + j] - local;
            r = (fabsf(r) > thr) ? r * C_SPIKE_D : r;
            xv[j] = (1.0f - C_TREND) * local + C_TREND * trend + C_DETAIL * r;
            if (j < 11) { s5 += w[9 + j] - w[4 + j]; s11 += w[12 + j] - w[1 + j]; }
        }
    } else {
        #pragma unroll
        for (int j = 0; j < 12; ++j) xv[j] = xp1_scalar(rp, L, o - 2 + j, thr);
    }

    // write owned xp1[o .. o+7] = xv[2..9]
    float* op = xp1 + (size_t)row * L + o;
    reinterpret_cast<float4*>(op)[0] = make_float4(xv[2], xv[3], xv[4], xv[5]);
    reinterpret_cast<float4*>(op)[1] = make_float4(xv[6], xv[7], xv[8], xv[9]);

    // pass-2 residual partials for owned positions
    double s = 0.0, s2 = 0.0;
    float t5 = xv[0] + xv[1] + xv[2] + xv[3] + xv[4];
    #pragma unroll
    for (int k = 0; k < EPT; ++k) {
        float r2 = xv[2 + k] - t5 * 0.2f;
        s += (double)r2;
        s2 = fma((double)r2, (double)r2, s2);
        if (k < EPT - 1) t5 += xv[5 + k] - xv[k];
    }
    block_partial_out(s, s2, partials2);
}

// ---- Stage 3: pass-2 apply (reads partials2 for thr) ----
__global__ __launch_bounds__(NTHREADS) void apply2_kernel(
    const float* __restrict__ in, float* __restrict__ out,
    const double* __restrict__ partials2, int L, int bpr) {
    int row = blockIdx.x / bpr;
    int chunk = blockIdx.x % bpr;
    const float* rp = in + (size_t)row * L;
    float* op = out + (size_t)row * L;

    float thr = block_thr(partials2 + (size_t)row * bpr * 2, bpr, L);

    int o = chunk * CHUNK + threadIdx.x * EPT;

    float w[24];
    if (o >= 8 && o + 16 <= L) {
        const float4* p = reinterpret_cast<const float4*>(rp + o - 8);
        #pragma unroll
        for (int j = 0; j < 6; ++j) {
            float4 v = p[j];
            w[4*j+0] = v.x; w[4*j+1] = v.y; w[4*j+2] = v.z; w[4*j+3] = v.w;
        }
    } else {
        #pragma unroll
        for (int j = 0; j < 24; ++j) w[j] = reflect_load(rp, o - 8 + j, L);
    }

    float s5  = w[6] + w[7] + w[8] + w[9] + w[10];
    float s11 = w[3] + w[4] + w[5] + w[6] + w[7] + w[8] + w[9] + w[10] + w[11] + w[12] + w[13];
    float res[EPT];
    #pragma unroll
    for (int k = 0; k < EPT; ++k) {
        float local = s5 * 0.2f;
        float trend = s11 * (1.0f / 11.0f);
        float x = w[8 + k];
        float r = x - local;
        r = (fabsf(r) > thr) ? r * C_SPIKE_D : r;
        res[k] = (1.0f - C_TREND) * local + C_TREND * trend + C_DETAIL * r;
        if (k < EPT - 1) { s5 += w[11 + k] - w[6 + k]; s11 += w[14 + k] - w[3 + k]; }
    }

    float4* q = reinterpret_cast<float4*>(op + o);
    q[0] = make_float4(res[0], res[1], res[2], res[3]);
    q[1] = make_float4(res[4], res[5], res[6], res[7]);
}

extern "C" void kernel_launch(void* const* d_in, const int* in_sizes, int n_in,
                              void* d_out, int out_size, void* d_ws, size_t ws_size,
                              hipStream_t stream) {
    const float* x = (const float*)d_in[0];
    float* outp = (float*)d_out;

    const int ROWS = 16;           // B*C = 4*4
    int total = in_sizes[0];
    int L = total / ROWS;          // 1048576
    int bpr = L / CHUNK;           // 512
    int nblocks = ROWS * bpr;      // 8192

    // workspace layout: [xp1 64MB][partials1 128KB][partials2 128KB]
    float* xp1 = (float*)d_ws;
    size_t inter_bytes = (size_t)total * sizeof(float);
    double* partials1 = (double*)((char*)d_ws + inter_bytes);
    double* partials2 = partials1 + (size_t)nblocks * 2;

    reduce1_kernel     <<<nblocks, NTHREADS, 0, stream>>>(x, partials1, L, bpr);
    fused_apply1_kernel<<<nblocks, NTHREADS, 0, stream>>>(x, xp1, partials1, partials2, L, bpr);
    apply2_kernel      <<<nblocks, NTHREADS, 0, stream>>>(xp1, outp, partials2, L, bpr);
}